// Round 5
// baseline (2956.664 us; speedup 1.0000x reference)
//
#include <hip/hip_runtime.h>

#define D 128

using short8 = __attribute__((ext_vector_type(8))) short;
using f32x4  = __attribute__((ext_vector_type(4))) float;

__device__ __forceinline__ unsigned short f2bf(float f) {
    unsigned int u = __builtin_bit_cast(unsigned int, f);
    unsigned int r = (u + 0x7fffu + ((u >> 16) & 1u)) >> 16;  // RNE
    return (unsigned short)r;
}

__device__ __forceinline__ short8 pack8(f32x4 a, f32x4 b) {
    short8 r;
    r[0] = (short)f2bf(a[0]); r[1] = (short)f2bf(a[1]);
    r[2] = (short)f2bf(a[2]); r[3] = (short)f2bf(a[3]);
    r[4] = (short)f2bf(b[0]); r[5] = (short)f2bf(b[1]);
    r[6] = (short)f2bf(b[2]); r[7] = (short)f2bf(b[3]);
    return r;
}

// ---------------------------------------------------------------------------
// K0: build bf16 B-fragment tables in frag order so GEMM blocks can stage them
// LDS-linearly and read conflict-free ds_read_b128.
// BfragC: [ct(8)][kc(4)][lane(64)][i(8)]  from Cw  (16x16x32 B-operand layout)
// BfragN: [cg(2)][ct(16)][kc(4)][lane(64)][i(8)] from concat(Aw,Bw,Vw,Uw)
// B[k][n]: lane holds k = kc*32 + (lane>>4)*8 + i,  n = ct*16 + (lane&15)
// ---------------------------------------------------------------------------
__global__ void __launch_bounds__(256) prep_frags(
    const float* __restrict__ Aw, const float* __restrict__ Bw,
    const float* __restrict__ Cw, const float* __restrict__ Uw,
    const float* __restrict__ Vw,
    unsigned short* __restrict__ BfragC, unsigned short* __restrict__ BfragN)
{
    int t = blockIdx.x * 256 + threadIdx.x;
    if (t < 2048) {
        int lane = t & 63;
        int slot = t >> 6;
        int kc = slot & 3, ct = slot >> 2;
        int n  = ct * 16 + (lane & 15);
        int kb = kc * 32 + (lane >> 4) * 8;
        #pragma unroll
        for (int i = 0; i < 8; ++i)
            BfragC[t * 8 + i] = f2bf(Cw[(kb + i) * D + n]);
    } else if (t < 2048 + 8192) {
        int u = t - 2048;
        int lane = u & 63;
        int slot = u >> 6;
        int kc = slot & 3, ct = (slot >> 2) & 15, cg = slot >> 6;
        int n512 = cg * 256 + ct * 16 + (lane & 15);
        int m = n512 >> 7, d = n512 & 127;
        const float* W = (m == 0) ? Aw : (m == 1) ? Bw : (m == 2) ? Vw : Uw;
        int kb = kc * 32 + (lane >> 4) * 8;
        #pragma unroll
        for (int i = 0; i < 8; ++i)
            BfragN[u * 8 + i] = f2bf(W[(kb + i) * D + d]);
    }
}

// ---------------------------------------------------------------------------
// K1: node GEMM  [N,128] @ [128,512] -> hA|hB|hV|hU (bias folded in).
// Block: 256 thr / 4 waves, 256 rows x 256 cols (grid.y selects col-group).
// ---------------------------------------------------------------------------
__global__ void __launch_bounds__(256) node_gemm(
    const float* __restrict__ h, const unsigned short* __restrict__ BfragN,
    const float* __restrict__ Ab, const float* __restrict__ Bb,
    const float* __restrict__ Vb, const float* __restrict__ Ub,
    float* __restrict__ hA, float* __restrict__ hB,
    float* __restrict__ hV, float* __restrict__ hU, int N)
{
    __shared__ unsigned short lbf[32768];  // 64 KB: 16ct*4kc*64lane*8 bf16
    const int tid = threadIdx.x, lane = tid & 63, wave = tid >> 6;
    const int cg = blockIdx.y;
    {
        const f32x4* src = (const f32x4*)(BfragN + (size_t)cg * 32768);
        f32x4* dst = (f32x4*)lbf;
        for (int i = tid; i < 4096; i += 256) dst[i] = src[i];
    }
    const int rowWave = blockIdx.x * 256 + wave * 64;
    short8 afr[4][4];  // [row-tile][kc]  A: row=lane&15, k=kc*32+(lane>>4)*8+i
    #pragma unroll
    for (int rt = 0; rt < 4; ++rt) {
        int row = rowWave + rt * 16 + (lane & 15);
        row = min(row, N - 1);
        const float* hp = h + (size_t)row * D + (lane >> 4) * 8;
        #pragma unroll
        for (int kc = 0; kc < 4; ++kc) {
            f32x4 x0 = *(const f32x4*)(hp + kc * 32);
            f32x4 x1 = *(const f32x4*)(hp + kc * 32 + 4);
            afr[rt][kc] = pack8(x0, x1);
        }
    }
    __syncthreads();
    #pragma unroll 1
    for (int ct = 0; ct < 16; ++ct) {
        f32x4 acc[4];
        #pragma unroll
        for (int rt = 0; rt < 4; ++rt) acc[rt] = (f32x4){0.f, 0.f, 0.f, 0.f};
        #pragma unroll
        for (int kc = 0; kc < 4; ++kc) {
            short8 bfr = *(const short8*)(lbf + ((size_t)(ct * 4 + kc) * 64 + lane) * 8);
            #pragma unroll
            for (int rt = 0; rt < 4; ++rt)
                acc[rt] = __builtin_amdgcn_mfma_f32_16x16x32_bf16(afr[rt][kc], bfr, acc[rt], 0, 0, 0);
        }
        int n512 = cg * 256 + ct * 16 + (lane & 15);
        int m = n512 >> 7, d = n512 & 127;   // which matrix / its column
        const float* bias = (m == 0) ? Ab : (m == 1) ? Bb : (m == 2) ? Vb : Ub;
        float* dstp       = (m == 0) ? hA : (m == 1) ? hB : (m == 2) ? hV : hU;
        float bv = bias[d];
        #pragma unroll
        for (int rt = 0; rt < 4; ++rt) {
            int rbase = rowWave + rt * 16 + ((lane >> 4) * 4);
            #pragma unroll
            for (int j = 0; j < 4; ++j) {
                int row = rbase + j;
                if (row < N) dstp[(size_t)row * D + d] = acc[rt][j] + bv;
            }
        }
    }
}

// ---------------------------------------------------------------------------
// K2: edge GEMM eta = e@Cw + Cb + hA[s] + hB[r]; writes eta f32 into the
// e_new region of d_out (overwritten in-place by K3); accumulates per-column
// sum/sumsq for BN (shfl reduce -> per-wave LDS bins -> 32-way-spread atomics)
// ---------------------------------------------------------------------------
__global__ void __launch_bounds__(256) edge_gemm(
    const float* __restrict__ e, const int* __restrict__ senders,
    const int* __restrict__ receivers, const unsigned short* __restrict__ BfragC,
    const float* __restrict__ Cb, const float* __restrict__ hA,
    const float* __restrict__ hB, float* __restrict__ etaout,
    float* __restrict__ estats, int E)
{
    __shared__ unsigned short lbf[16384];   // 32 KB
    __shared__ float lstats[4][256];        // per-wave sum[128]+sumsq[128]
    const int tid = threadIdx.x, lane = tid & 63, wave = tid >> 6;
    {
        const f32x4* src = (const f32x4*)BfragC;
        f32x4* dst = (f32x4*)lbf;
        for (int i = tid; i < 2048; i += 256) dst[i] = src[i];
    }
    for (int i = lane; i < 256; i += 64) lstats[wave][i] = 0.f;
    const int ebase = blockIdx.x * 256 + wave * 64;
    short8 afr[4][4];
    #pragma unroll
    for (int rt = 0; rt < 4; ++rt) {
        int row = ebase + rt * 16 + (lane & 15);
        row = min(row, E - 1);
        const float* ep = e + (size_t)row * D + (lane >> 4) * 8;
        #pragma unroll
        for (int kc = 0; kc < 4; ++kc) {
            f32x4 x0 = *(const f32x4*)(ep + kc * 32);
            f32x4 x1 = *(const f32x4*)(ep + kc * 32 + 4);
            afr[rt][kc] = pack8(x0, x1);
        }
    }
    int sidx[4][4], ridx[4][4];   // epilogue rows this lane owns (C/D layout)
    #pragma unroll
    for (int rt = 0; rt < 4; ++rt) {
        #pragma unroll
        for (int j = 0; j < 4; ++j) {
            int ed = ebase + rt * 16 + ((lane >> 4) * 4) + j;
            int ec = min(ed, E - 1);
            sidx[rt][j] = senders[ec];
            ridx[rt][j] = receivers[ec];
        }
    }
    __syncthreads();
    #pragma unroll 1
    for (int ct = 0; ct < 8; ++ct) {
        f32x4 acc[4];
        #pragma unroll
        for (int rt = 0; rt < 4; ++rt) acc[rt] = (f32x4){0.f, 0.f, 0.f, 0.f};
        #pragma unroll
        for (int kc = 0; kc < 4; ++kc) {
            short8 bfr = *(const short8*)(lbf + ((size_t)(ct * 4 + kc) * 64 + lane) * 8);
            #pragma unroll
            for (int rt = 0; rt < 4; ++rt)
                acc[rt] = __builtin_amdgcn_mfma_f32_16x16x32_bf16(afr[rt][kc], bfr, acc[rt], 0, 0, 0);
        }
        int col = ct * 16 + (lane & 15);
        float cb = Cb[col];
        float ps = 0.f, ps2 = 0.f;
        #pragma unroll
        for (int rt = 0; rt < 4; ++rt) {
            int rbase = ebase + rt * 16 + ((lane >> 4) * 4);
            #pragma unroll
            for (int j = 0; j < 4; ++j) {
                int ed = rbase + j;
                if (ed < E) {
                    float v = acc[rt][j] + cb
                            + hA[(size_t)sidx[rt][j] * D + col]
                            + hB[(size_t)ridx[rt][j] * D + col];
                    etaout[(size_t)ed * D + col] = v;
                    ps  += v;
                    ps2 += v * v;
                }
            }
        }
        ps  += __shfl_xor(ps, 16);  ps  += __shfl_xor(ps, 32);
        ps2 += __shfl_xor(ps2, 16); ps2 += __shfl_xor(ps2, 32);
        if (lane < 16) {                       // distinct cols, wave-serial: no atomics
            lstats[wave][col]       += ps;
            lstats[wave][128 + col] += ps2;
        }
    }
    __syncthreads();
    float v = lstats[0][tid] + lstats[1][tid] + lstats[2][tid] + lstats[3][tid];
    unsafeAtomicAdd(&estats[(blockIdx.x & 31) * 256 + tid], v);
}

// ---------------------------------------------------------------------------
// finalize BN stats: 32 spread copies -> scale/shift vectors
// ---------------------------------------------------------------------------
__global__ void finalize_stats(const float* __restrict__ stats,
    const float* __restrict__ scale, const float* __restrict__ offset,
    float* __restrict__ scsh, float cnt)
{
    int c = threadIdx.x;
    if (c >= 128) return;
    float s = 0.f, s2 = 0.f;
    for (int b = 0; b < 32; ++b) { s += stats[b * 256 + c]; s2 += stats[b * 256 + 128 + c]; }
    float mean = s / cnt;
    float var  = fmaxf(s2 / cnt - mean * mean, 0.f);
    float rs   = rsqrtf(var + 1e-5f);
    float sc   = scale[c] * rs;
    scsh[c]       = sc;
    scsh[128 + c] = offset[c] - mean * sc;
}

// ---------------------------------------------------------------------------
// K3: edge elementwise: e_new = e + relu(BN(eta)); w = sigmoid(e_new);
// scatter-add w and hV[r]*w into wsum/agg (segment sums over senders).
// ---------------------------------------------------------------------------
__global__ void __launch_bounds__(256) edge_pass_kernel(
    const float* __restrict__ e, const int* __restrict__ senders,
    const int* __restrict__ receivers, const float* __restrict__ scsh,
    const float* __restrict__ hV, float* __restrict__ e_out,
    float* __restrict__ agg, float* __restrict__ wsum, int E)
{
    int idx = blockIdx.x * 256 + threadIdx.x;
    if (idx >= E * 32) return;
    int edge = idx >> 5;
    int c0 = (idx & 31) * 4;
    size_t rowoff = (size_t)edge * D + c0;
    f32x4 ev = *(const f32x4*)(e + rowoff);
    f32x4 et = *(const f32x4*)(e_out + rowoff);   // eta written by K2
    f32x4 sc = *(const f32x4*)(scsh + c0);
    f32x4 sh = *(const f32x4*)(scsh + 128 + c0);
    int s = senders[edge], r = receivers[edge];
    f32x4 hv = *(const f32x4*)(hV + (size_t)r * D + c0);
    f32x4 en;
    #pragma unroll
    for (int k = 0; k < 4; ++k) {
        float f = fmaxf(et[k] * sc[k] + sh[k], 0.f);
        en[k] = ev[k] + f;
    }
    *(f32x4*)(e_out + rowoff) = en;
    float* wp = wsum + (size_t)s * D + c0;
    float* ap = agg  + (size_t)s * D + c0;
    #pragma unroll
    for (int k = 0; k < 4; ++k) {
        float w = 1.f / (1.f + __expf(-en[k]));
        unsafeAtomicAdd(wp + k, w);
        unsafeAtomicAdd(ap + k, hv[k] * w);
    }
}

// ---------------------------------------------------------------------------
// K4a: node_feat = hU + agg/(wsum+1e-6); store + BN stats partials
// ---------------------------------------------------------------------------
__global__ void __launch_bounds__(256) node_feat_kernel(
    const float* __restrict__ hU, const float* __restrict__ agg,
    const float* __restrict__ wsum, float* __restrict__ nf,
    float* __restrict__ nstats, int N)
{
    int idx = blockIdx.x * 256 + threadIdx.x;
    int lane = threadIdx.x & 63;
    bool valid = idx < N * 32;
    int i4 = idx * 4;
    f32x4 p = (f32x4){0.f, 0.f, 0.f, 0.f}, p2 = (f32x4){0.f, 0.f, 0.f, 0.f};
    if (valid) {
        f32x4 u = *(const f32x4*)(hU + i4);
        f32x4 a = *(const f32x4*)(agg + i4);
        f32x4 w = *(const f32x4*)(wsum + i4);
        f32x4 v;
        #pragma unroll
        for (int k = 0; k < 4; ++k) v[k] = u[k] + a[k] / (w[k] + 1e-6f);
        *(f32x4*)(nf + i4) = v;
        p = v;
        #pragma unroll
        for (int k = 0; k < 4; ++k) p2[k] = v[k] * v[k];
    }
    #pragma unroll
    for (int k = 0; k < 4; ++k) {   // lane and lane^32 handle the same columns
        p[k]  += __shfl_xor(p[k], 32);
        p2[k] += __shfl_xor(p2[k], 32);
    }
    if (lane < 32) {
        int c0 = i4 & 127;
        float* sb = nstats + (blockIdx.x & 31) * 256;
        #pragma unroll
        for (int k = 0; k < 4; ++k) {
            unsafeAtomicAdd(sb + c0 + k, p[k]);
            unsafeAtomicAdd(sb + 128 + c0 + k, p2[k]);
        }
    }
}

// ---------------------------------------------------------------------------
// K4c: h_new = h + relu(BN(node_feat))
// ---------------------------------------------------------------------------
__global__ void __launch_bounds__(256) node_out_kernel(
    const float* __restrict__ h, const float* __restrict__ nf,
    const float* __restrict__ scsh, float* __restrict__ out, int N)
{
    int idx = blockIdx.x * 256 + threadIdx.x;
    if (idx >= N * 32) return;
    int i4 = idx * 4;
    int c0 = i4 & 127;
    f32x4 hh = *(const f32x4*)(h + i4);
    f32x4 v  = *(const f32x4*)(nf + i4);
    f32x4 sc = *(const f32x4*)(scsh + c0);
    f32x4 sh = *(const f32x4*)(scsh + 128 + c0);
    f32x4 o;
    #pragma unroll
    for (int k = 0; k < 4; ++k) {
        float f = fmaxf(v[k] * sc[k] + sh[k], 0.f);
        o[k] = hh[k] + f;
    }
    *(f32x4*)(out + i4) = o;
}

// ---------------------------------------------------------------------------
extern "C" void kernel_launch(void* const* d_in, const int* in_sizes, int n_in,
                              void* d_out, int out_size, void* d_ws, size_t ws_size,
                              hipStream_t stream)
{
    const float* h  = (const float*)d_in[0];
    const float* e  = (const float*)d_in[1];
    const int* senders   = (const int*)d_in[2];
    const int* receivers = (const int*)d_in[3];
    const float* Aw = (const float*)d_in[4];
    const float* Ab = (const float*)d_in[5];
    const float* Bw = (const float*)d_in[6];
    const float* Bb = (const float*)d_in[7];
    const float* Cw = (const float*)d_in[8];
    const float* Cb = (const float*)d_in[9];
    const float* Uw = (const float*)d_in[10];
    const float* Ub = (const float*)d_in[11];
    const float* Vw = (const float*)d_in[12];
    const float* Vb = (const float*)d_in[13];
    const float* bnEs = (const float*)d_in[14];
    const float* bnEo = (const float*)d_in[15];
    const float* bnNs = (const float*)d_in[16];
    const float* bnNo = (const float*)d_in[17];

    const int N = in_sizes[0] / D;   // 50000
    const int E = in_sizes[1] / D;   // 600000

    float* out   = (float*)d_out;
    float* out_h = out;
    float* out_e = out + (size_t)N * D;

    // workspace layout (f32 units); ~128.3 MB in d_ws.
    // agg lives in the out_h region of d_out (dead until node_out_kernel,
    // which overwrites it last) to cut d_ws footprint.
    float* ws     = (float*)d_ws;
    float* hA     = ws;
    float* hB     = hA + (size_t)N * D;
    float* hV     = hB + (size_t)N * D;
    float* hU     = hV + (size_t)N * D;
    float* wsum   = hU + (size_t)N * D;
    float* estats = wsum + (size_t)N * D;   // 32*256
    float* nstats = estats + 32 * 256;      // 32*256
    float* scsh_e = nstats + 32 * 256;      // 256
    float* scsh_n = scsh_e + 256;           // 256
    unsigned short* BfragC = (unsigned short*)(scsh_n + 256);  // 16384 ushort
    unsigned short* BfragN = BfragC + 16384;                   // 65536 ushort
    float* agg = out_h;   // alias into d_out
    float* nf  = hA;      // alias: hA dead after edge_gemm

    // zero agg (in d_out) and wsum+estats+nstats (contiguous in ws)
    hipMemsetAsync(agg, 0, (size_t)N * D * sizeof(float), stream);
    hipMemsetAsync(wsum, 0, ((size_t)N * D + 2 * 32 * 256) * sizeof(float), stream);

    prep_frags<<<40, 256, 0, stream>>>(Aw, Bw, Cw, Uw, Vw, BfragC, BfragN);

    dim3 g1((N + 255) / 256, 2);
    node_gemm<<<g1, 256, 0, stream>>>(h, BfragN, Ab, Bb, Vb, Ub, hA, hB, hV, hU, N);

    edge_gemm<<<(E + 255) / 256, 256, 0, stream>>>(e, senders, receivers, BfragC, Cb,
                                                   hA, hB, out_e, estats, E);
    finalize_stats<<<1, 128, 0, stream>>>(estats, bnEs, bnEo, scsh_e, (float)E);

    edge_pass_kernel<<<(E * 32 + 255) / 256, 256, 0, stream>>>(e, senders, receivers,
                                                               scsh_e, hV, out_e, agg, wsum, E);

    node_feat_kernel<<<(N * 32 + 255) / 256, 256, 0, stream>>>(hU, agg, wsum, nf, nstats, N);
    finalize_stats<<<1, 128, 0, stream>>>(nstats, bnNs, bnNo, scsh_n, (float)N);
    node_out_kernel<<<(N * 32 + 255) / 256, 256, 0, stream>>>(h, nf, scsh_n, out_h, N);
}

// Round 6
// 1423.455 us; speedup vs baseline: 2.0771x; 2.0771x over previous
//
#include <hip/hip_runtime.h>

#define D 128

using short8 = __attribute__((ext_vector_type(8))) short;
using f32x4  = __attribute__((ext_vector_type(4))) float;

__device__ __forceinline__ unsigned short f2bf(float f) {
    unsigned int u = __builtin_bit_cast(unsigned int, f);
    unsigned int r = (u + 0x7fffu + ((u >> 16) & 1u)) >> 16;  // RNE
    return (unsigned short)r;
}

__device__ __forceinline__ short8 pack8(f32x4 a, f32x4 b) {
    short8 r;
    r[0] = (short)f2bf(a[0]); r[1] = (short)f2bf(a[1]);
    r[2] = (short)f2bf(a[2]); r[3] = (short)f2bf(a[3]);
    r[4] = (short)f2bf(b[0]); r[5] = (short)f2bf(b[1]);
    r[6] = (short)f2bf(b[2]); r[7] = (short)f2bf(b[3]);
    return r;
}

// ---------------------------------------------------------------------------
// K0: build bf16 B-fragment tables in frag order (see round-0 notes).
// ---------------------------------------------------------------------------
__global__ void __launch_bounds__(256) prep_frags(
    const float* __restrict__ Aw, const float* __restrict__ Bw,
    const float* __restrict__ Cw, const float* __restrict__ Uw,
    const float* __restrict__ Vw,
    unsigned short* __restrict__ BfragC, unsigned short* __restrict__ BfragN)
{
    int t = blockIdx.x * 256 + threadIdx.x;
    if (t < 2048) {
        int lane = t & 63;
        int slot = t >> 6;
        int kc = slot & 3, ct = slot >> 2;
        int n  = ct * 16 + (lane & 15);
        int kb = kc * 32 + (lane >> 4) * 8;
        #pragma unroll
        for (int i = 0; i < 8; ++i)
            BfragC[t * 8 + i] = f2bf(Cw[(kb + i) * D + n]);
    } else if (t < 2048 + 8192) {
        int u = t - 2048;
        int lane = u & 63;
        int slot = u >> 6;
        int kc = slot & 3, ct = (slot >> 2) & 15, cg = slot >> 6;
        int n512 = cg * 256 + ct * 16 + (lane & 15);
        int m = n512 >> 7, d = n512 & 127;
        const float* W = (m == 0) ? Aw : (m == 1) ? Bw : (m == 2) ? Vw : Uw;
        int kb = kc * 32 + (lane >> 4) * 8;
        #pragma unroll
        for (int i = 0; i < 8; ++i)
            BfragN[u * 8 + i] = f2bf(W[(kb + i) * D + d]);
    }
}

// ---------------------------------------------------------------------------
// K1: node GEMM  [N,128] @ [128,512] -> hA|hB|hV|hU (bias folded in).
// ---------------------------------------------------------------------------
__global__ void __launch_bounds__(256) node_gemm(
    const float* __restrict__ h, const unsigned short* __restrict__ BfragN,
    const float* __restrict__ Ab, const float* __restrict__ Bb,
    const float* __restrict__ Vb, const float* __restrict__ Ub,
    float* __restrict__ hA, float* __restrict__ hB,
    float* __restrict__ hV, float* __restrict__ hU, int N)
{
    __shared__ unsigned short lbf[32768];  // 64 KB
    const int tid = threadIdx.x, lane = tid & 63, wave = tid >> 6;
    const int cg = blockIdx.y;
    {
        const f32x4* src = (const f32x4*)(BfragN + (size_t)cg * 32768);
        f32x4* dst = (f32x4*)lbf;
        for (int i = tid; i < 4096; i += 256) dst[i] = src[i];
    }
    const int rowWave = blockIdx.x * 256 + wave * 64;
    short8 afr[4][4];
    #pragma unroll
    for (int rt = 0; rt < 4; ++rt) {
        int row = rowWave + rt * 16 + (lane & 15);
        row = min(row, N - 1);
        const float* hp = h + (size_t)row * D + (lane >> 4) * 8;
        #pragma unroll
        for (int kc = 0; kc < 4; ++kc) {
            f32x4 x0 = *(const f32x4*)(hp + kc * 32);
            f32x4 x1 = *(const f32x4*)(hp + kc * 32 + 4);
            afr[rt][kc] = pack8(x0, x1);
        }
    }
    __syncthreads();
    #pragma unroll 1
    for (int ct = 0; ct < 16; ++ct) {
        f32x4 acc[4];
        #pragma unroll
        for (int rt = 0; rt < 4; ++rt) acc[rt] = (f32x4){0.f, 0.f, 0.f, 0.f};
        #pragma unroll
        for (int kc = 0; kc < 4; ++kc) {
            short8 bfr = *(const short8*)(lbf + ((size_t)(ct * 4 + kc) * 64 + lane) * 8);
            #pragma unroll
            for (int rt = 0; rt < 4; ++rt)
                acc[rt] = __builtin_amdgcn_mfma_f32_16x16x32_bf16(afr[rt][kc], bfr, acc[rt], 0, 0, 0);
        }
        int n512 = cg * 256 + ct * 16 + (lane & 15);
        int m = n512 >> 7, d = n512 & 127;
        const float* bias = (m == 0) ? Ab : (m == 1) ? Bb : (m == 2) ? Vb : Ub;
        float* dstp       = (m == 0) ? hA : (m == 1) ? hB : (m == 2) ? hV : hU;
        float bv = bias[d];
        #pragma unroll
        for (int rt = 0; rt < 4; ++rt) {
            int rbase = rowWave + rt * 16 + ((lane >> 4) * 4);
            #pragma unroll
            for (int j = 0; j < 4; ++j) {
                int row = rbase + j;
                if (row < N) dstp[(size_t)row * D + d] = acc[rt][j] + bv;
            }
        }
    }
}

// ---------------------------------------------------------------------------
// K2: edge GEMM eta = e@Cw + Cb + hA[s] + hB[r]; eta f32 -> e_new region of
// d_out (overwritten in-place by edge_bn); BN stats via LDS bins + atomics.
// ---------------------------------------------------------------------------
__global__ void __launch_bounds__(256) edge_gemm(
    const float* __restrict__ e, const int* __restrict__ senders,
    const int* __restrict__ receivers, const unsigned short* __restrict__ BfragC,
    const float* __restrict__ Cb, const float* __restrict__ hA,
    const float* __restrict__ hB, float* __restrict__ etaout,
    float* __restrict__ estats, int E)
{
    __shared__ unsigned short lbf[16384];   // 32 KB
    __shared__ float lstats[4][256];
    const int tid = threadIdx.x, lane = tid & 63, wave = tid >> 6;
    {
        const f32x4* src = (const f32x4*)BfragC;
        f32x4* dst = (f32x4*)lbf;
        for (int i = tid; i < 2048; i += 256) dst[i] = src[i];
    }
    for (int i = lane; i < 256; i += 64) lstats[wave][i] = 0.f;
    const int ebase = blockIdx.x * 256 + wave * 64;
    short8 afr[4][4];
    #pragma unroll
    for (int rt = 0; rt < 4; ++rt) {
        int row = ebase + rt * 16 + (lane & 15);
        row = min(row, E - 1);
        const float* ep = e + (size_t)row * D + (lane >> 4) * 8;
        #pragma unroll
        for (int kc = 0; kc < 4; ++kc) {
            f32x4 x0 = *(const f32x4*)(ep + kc * 32);
            f32x4 x1 = *(const f32x4*)(ep + kc * 32 + 4);
            afr[rt][kc] = pack8(x0, x1);
        }
    }
    int sidx[4][4], ridx[4][4];
    #pragma unroll
    for (int rt = 0; rt < 4; ++rt) {
        #pragma unroll
        for (int j = 0; j < 4; ++j) {
            int ed = ebase + rt * 16 + ((lane >> 4) * 4) + j;
            int ec = min(ed, E - 1);
            sidx[rt][j] = senders[ec];
            ridx[rt][j] = receivers[ec];
        }
    }
    __syncthreads();
    #pragma unroll 1
    for (int ct = 0; ct < 8; ++ct) {
        f32x4 acc[4];
        #pragma unroll
        for (int rt = 0; rt < 4; ++rt) acc[rt] = (f32x4){0.f, 0.f, 0.f, 0.f};
        #pragma unroll
        for (int kc = 0; kc < 4; ++kc) {
            short8 bfr = *(const short8*)(lbf + ((size_t)(ct * 4 + kc) * 64 + lane) * 8);
            #pragma unroll
            for (int rt = 0; rt < 4; ++rt)
                acc[rt] = __builtin_amdgcn_mfma_f32_16x16x32_bf16(afr[rt][kc], bfr, acc[rt], 0, 0, 0);
        }
        int col = ct * 16 + (lane & 15);
        float cb = Cb[col];
        float ps = 0.f, ps2 = 0.f;
        #pragma unroll
        for (int rt = 0; rt < 4; ++rt) {
            int rbase = ebase + rt * 16 + ((lane >> 4) * 4);
            #pragma unroll
            for (int j = 0; j < 4; ++j) {
                int ed = rbase + j;
                if (ed < E) {
                    float v = acc[rt][j] + cb
                            + hA[(size_t)sidx[rt][j] * D + col]
                            + hB[(size_t)ridx[rt][j] * D + col];
                    etaout[(size_t)ed * D + col] = v;
                    ps  += v;
                    ps2 += v * v;
                }
            }
        }
        ps  += __shfl_xor(ps, 16);  ps  += __shfl_xor(ps, 32);
        ps2 += __shfl_xor(ps2, 16); ps2 += __shfl_xor(ps2, 32);
        if (lane < 16) {
            lstats[wave][col]       += ps;
            lstats[wave][128 + col] += ps2;
        }
    }
    __syncthreads();
    float v = lstats[0][tid] + lstats[1][tid] + lstats[2][tid] + lstats[3][tid];
    unsafeAtomicAdd(&estats[(blockIdx.x & 31) * 256 + tid], v);
}

// ---------------------------------------------------------------------------
// finalize BN stats: 32 spread copies -> scale/shift vectors
// ---------------------------------------------------------------------------
__global__ void finalize_stats(const float* __restrict__ stats,
    const float* __restrict__ scale, const float* __restrict__ offset,
    float* __restrict__ scsh, float cnt)
{
    int c = threadIdx.x;
    if (c >= 128) return;
    float s = 0.f, s2 = 0.f;
    for (int b = 0; b < 32; ++b) { s += stats[b * 256 + c]; s2 += stats[b * 256 + 128 + c]; }
    float mean = s / cnt;
    float var  = fmaxf(s2 / cnt - mean * mean, 0.f);
    float rs   = rsqrtf(var + 1e-5f);
    float sc   = scale[c] * rs;
    scsh[c]       = sc;
    scsh[128 + c] = offset[c] - mean * sc;
}

// ---------------------------------------------------------------------------
// K3: edge BN apply (pure streaming, NO atomics): e_new = e + relu(BN(eta))
// ---------------------------------------------------------------------------
__global__ void __launch_bounds__(256) edge_bn_kernel(
    const float* __restrict__ e, const float* __restrict__ scsh,
    float* __restrict__ e_out, int total4)
{
    int idx = blockIdx.x * 256 + threadIdx.x;
    if (idx >= total4) return;
    size_t off = (size_t)idx * 4;
    int c0 = (int)(off & 127);
    f32x4 ev = *(const f32x4*)(e + off);
    f32x4 et = *(const f32x4*)(e_out + off);   // eta from edge_gemm
    f32x4 sc = *(const f32x4*)(scsh + c0);
    f32x4 sh = *(const f32x4*)(scsh + 128 + c0);
    f32x4 en;
    #pragma unroll
    for (int k = 0; k < 4; ++k) {
        float f = fmaxf(et[k] * sc[k] + sh[k], 0.f);
        en[k] = ev[k] + f;
    }
    *(f32x4*)(e_out + off) = en;
}

// ---------------------------------------------------------------------------
// CSR build: histogram -> single-block scan -> fill (edge ids per sender)
// ---------------------------------------------------------------------------
__global__ void __launch_bounds__(256) csr_hist(
    const int* __restrict__ senders, int* __restrict__ counts, int E)
{
    int i = blockIdx.x * 256 + threadIdx.x;
    if (i < E) atomicAdd(&counts[senders[i]], 1);
}

__global__ void __launch_bounds__(1024) csr_scan(
    const int* __restrict__ counts, int* __restrict__ rowstart,
    int* __restrict__ cursor, int N)
{
    __shared__ int psum[1024];
    int tid = threadIdx.x;
    int chunk = (N + 1023) / 1024;
    int lo = tid * chunk, hi = min(lo + chunk, N);
    if (lo > N) lo = N;
    if (hi < lo) hi = lo;
    int s = 0;
    for (int i = lo; i < hi; ++i) s += counts[i];
    psum[tid] = s;
    __syncthreads();
    for (int off = 1; off < 1024; off <<= 1) {   // Hillis-Steele inclusive scan
        int v = (tid >= off) ? psum[tid - off] : 0;
        __syncthreads();
        psum[tid] += v;
        __syncthreads();
    }
    int base = (tid == 0) ? 0 : psum[tid - 1];
    for (int i = lo; i < hi; ++i) {
        rowstart[i] = base;
        cursor[i]   = base;
        base += counts[i];
    }
    if (tid == 1023) rowstart[N] = psum[1023];
}

__global__ void __launch_bounds__(256) csr_fill(
    const int* __restrict__ senders, int* __restrict__ cursor,
    int* __restrict__ elist, int E)
{
    int i = blockIdx.x * 256 + threadIdx.x;
    if (i < E) {
        int pos = atomicAdd(&cursor[senders[i]], 1);
        elist[pos] = i;
    }
}

// ---------------------------------------------------------------------------
// K4: node aggregation PULL (no scatter atomics): for each node, walk its
// edge list, accumulate w=sigmoid(e_new) and hV[recv]*w in REGISTERS;
// fused node_feat = hU + a/(w+1e-6), write nf + BN stats partials.
// Block = 256 threads = 2 nodes x 128 cols.
// ---------------------------------------------------------------------------
__global__ void __launch_bounds__(256) node_agg_kernel(
    const float* __restrict__ e_new, const int* __restrict__ receivers,
    const int* __restrict__ rowstart, const int* __restrict__ elist,
    const float* __restrict__ hV, const float* __restrict__ hU,
    float* __restrict__ nf, float* __restrict__ nstats, int N)
{
    __shared__ float lsum[128], lsq[128];
    const int half = threadIdx.x >> 7;     // 0 or 1
    const int c    = threadIdx.x & 127;
    const int n    = blockIdx.x * 2 + half;
    float v = 0.f;
    if (n < N) {
        float w = 0.f, a = 0.f;
        int lo = rowstart[n], hi = rowstart[n + 1];
        for (int k = lo; k < hi; ++k) {
            int eidx = elist[k];
            int r    = receivers[eidx];
            float ev = e_new[(size_t)eidx * D + c];
            float sw = 1.f / (1.f + __expf(-ev));
            a += hV[(size_t)r * D + c] * sw;
            w += sw;
        }
        v = hU[(size_t)n * D + c] + a / (w + 1e-6f);
        nf[(size_t)n * D + c] = v;
    }
    if (half == 0) { lsum[c] = v;  lsq[c] = v * v; }
    __syncthreads();
    if (half == 1) { lsum[c] += v; lsq[c] += v * v; }
    __syncthreads();
    if (half == 0) {
        float* sb = nstats + (blockIdx.x & 31) * 256;
        unsafeAtomicAdd(sb + c, lsum[c]);
        unsafeAtomicAdd(sb + 128 + c, lsq[c]);
    }
}

// ---------------------------------------------------------------------------
// K5: h_new = h + relu(BN(node_feat))
// ---------------------------------------------------------------------------
__global__ void __launch_bounds__(256) node_out_kernel(
    const float* __restrict__ h, const float* __restrict__ nf,
    const float* __restrict__ scsh, float* __restrict__ out, int N)
{
    int idx = blockIdx.x * 256 + threadIdx.x;
    if (idx >= N * 32) return;
    size_t i4 = (size_t)idx * 4;
    int c0 = (int)(i4 & 127);
    f32x4 hh = *(const f32x4*)(h + i4);
    f32x4 v  = *(const f32x4*)(nf + i4);
    f32x4 sc = *(const f32x4*)(scsh + c0);
    f32x4 sh = *(const f32x4*)(scsh + 128 + c0);
    f32x4 o;
    #pragma unroll
    for (int k = 0; k < 4; ++k) {
        float f = fmaxf(v[k] * sc[k] + sh[k], 0.f);
        o[k] = hh[k] + f;
    }
    *(f32x4*)(out + i4) = o;
}

// ---------------------------------------------------------------------------
extern "C" void kernel_launch(void* const* d_in, const int* in_sizes, int n_in,
                              void* d_out, int out_size, void* d_ws, size_t ws_size,
                              hipStream_t stream)
{
    const float* h  = (const float*)d_in[0];
    const float* e  = (const float*)d_in[1];
    const int* senders   = (const int*)d_in[2];
    const int* receivers = (const int*)d_in[3];
    const float* Aw = (const float*)d_in[4];
    const float* Ab = (const float*)d_in[5];
    const float* Bw = (const float*)d_in[6];
    const float* Bb = (const float*)d_in[7];
    const float* Cw = (const float*)d_in[8];
    const float* Cb = (const float*)d_in[9];
    const float* Uw = (const float*)d_in[10];
    const float* Ub = (const float*)d_in[11];
    const float* Vw = (const float*)d_in[12];
    const float* Vb = (const float*)d_in[13];
    const float* bnEs = (const float*)d_in[14];
    const float* bnEo = (const float*)d_in[15];
    const float* bnNs = (const float*)d_in[16];
    const float* bnNo = (const float*)d_in[17];

    const int N = in_sizes[0] / D;   // 50000
    const int E = in_sizes[1] / D;   // 600000

    float* out   = (float*)d_out;
    float* out_h = out;
    float* out_e = out + (size_t)N * D;

    // workspace layout (f32 units); ~106 MB in d_ws
    float* ws     = (float*)d_ws;
    float* hA     = ws;
    float* hB     = hA + (size_t)N * D;
    float* hV     = hB + (size_t)N * D;
    float* hU     = hV + (size_t)N * D;
    float* estats = hU + (size_t)N * D;     // 32*256
    float* nstats = estats + 32 * 256;      // 32*256
    float* scsh_e = nstats + 32 * 256;      // 256
    float* scsh_n = scsh_e + 256;           // 256
    int* counts   = (int*)(scsh_n + 256);   // N
    int* rowstart = counts + N;             // N+1
    int* cursor   = rowstart + N + 1;       // N
    int* elist    = cursor + N;             // E
    unsigned short* BfragC = (unsigned short*)(elist + E);     // 16384 ushort
    unsigned short* BfragN = BfragC + 16384;                   // 65536 ushort
    float* nf = hA;   // alias: hA dead after edge_gemm

    // zero estats + nstats + scsh (overwritten anyway) + counts (contiguous)
    hipMemsetAsync(estats, 0, (size_t)(2 * 32 * 256 + 2 * 256 + N) * sizeof(float), stream);

    prep_frags<<<40, 256, 0, stream>>>(Aw, Bw, Cw, Uw, Vw, BfragC, BfragN);

    // CSR build (independent of GEMMs)
    csr_hist<<<(E + 255) / 256, 256, 0, stream>>>(senders, counts, E);
    csr_scan<<<1, 1024, 0, stream>>>(counts, rowstart, cursor, N);
    csr_fill<<<(E + 255) / 256, 256, 0, stream>>>(senders, cursor, elist, E);

    dim3 g1((N + 255) / 256, 2);
    node_gemm<<<g1, 256, 0, stream>>>(h, BfragN, Ab, Bb, Vb, Ub, hA, hB, hV, hU, N);

    edge_gemm<<<(E + 255) / 256, 256, 0, stream>>>(e, senders, receivers, BfragC, Cb,
                                                   hA, hB, out_e, estats, E);
    finalize_stats<<<1, 128, 0, stream>>>(estats, bnEs, bnEo, scsh_e, (float)E);

    edge_bn_kernel<<<(E * 32 + 255) / 256, 256, 0, stream>>>(e, scsh_e, out_e, E * 32);

    node_agg_kernel<<<(N + 1) / 2, 256, 0, stream>>>(out_e, receivers, rowstart, elist,
                                                     hV, hU, nf, nstats, N);
    finalize_stats<<<1, 128, 0, stream>>>(nstats, bnNs, bnNo, scsh_n, (float)N);
    node_out_kernel<<<(N * 32 + 255) / 256, 256, 0, stream>>>(h, nf, scsh_n, out_h, N);
}

// Round 9
// 1354.975 us; speedup vs baseline: 2.1821x; 1.0505x over previous
//
#include <hip/hip_runtime.h>

#define D 128

using short8 = __attribute__((ext_vector_type(8))) short;
using f32x4  = __attribute__((ext_vector_type(4))) float;

__device__ __forceinline__ unsigned short f2bf(float f) {
    unsigned int u = __builtin_bit_cast(unsigned int, f);
    unsigned int r = (u + 0x7fffu + ((u >> 16) & 1u)) >> 16;  // RNE
    return (unsigned short)r;
}

__device__ __forceinline__ float bf2f(unsigned short u) {
    unsigned int x = ((unsigned int)u) << 16;
    return __builtin_bit_cast(float, x);
}

__device__ __forceinline__ short8 pack8(f32x4 a, f32x4 b) {
    short8 r;
    r[0] = (short)f2bf(a[0]); r[1] = (short)f2bf(a[1]);
    r[2] = (short)f2bf(a[2]); r[3] = (short)f2bf(a[3]);
    r[4] = (short)f2bf(b[0]); r[5] = (short)f2bf(b[1]);
    r[6] = (short)f2bf(b[2]); r[7] = (short)f2bf(b[3]);
    return r;
}

// ---------------------------------------------------------------------------
// K0: build bf16 B-fragment tables in frag order (see round-0 notes).
// ---------------------------------------------------------------------------
__global__ void __launch_bounds__(256) prep_frags(
    const float* __restrict__ Aw, const float* __restrict__ Bw,
    const float* __restrict__ Cw, const float* __restrict__ Uw,
    const float* __restrict__ Vw,
    unsigned short* __restrict__ BfragC, unsigned short* __restrict__ BfragN)
{
    int t = blockIdx.x * 256 + threadIdx.x;
    if (t < 2048) {
        int lane = t & 63;
        int slot = t >> 6;
        int kc = slot & 3, ct = slot >> 2;
        int n  = ct * 16 + (lane & 15);
        int kb = kc * 32 + (lane >> 4) * 8;
        #pragma unroll
        for (int i = 0; i < 8; ++i)
            BfragC[t * 8 + i] = f2bf(Cw[(kb + i) * D + n]);
    } else if (t < 2048 + 8192) {
        int u = t - 2048;
        int lane = u & 63;
        int slot = u >> 6;
        int kc = slot & 3, ct = (slot >> 2) & 15, cg = slot >> 6;
        int n512 = cg * 256 + ct * 16 + (lane & 15);
        int m = n512 >> 7, d = n512 & 127;
        const float* W = (m == 0) ? Aw : (m == 1) ? Bw : (m == 2) ? Vw : Uw;
        int kb = kc * 32 + (lane >> 4) * 8;
        #pragma unroll
        for (int i = 0; i < 8; ++i)
            BfragN[u * 8 + i] = f2bf(W[(kb + i) * D + d]);
    }
}

// ---------------------------------------------------------------------------
// K1: node GEMM [N,128]@[128,512] -> hA|hB|hV (bf16 tables) + hU (f32).
// ---------------------------------------------------------------------------
__global__ void __launch_bounds__(256) node_gemm(
    const float* __restrict__ h, const unsigned short* __restrict__ BfragN,
    const float* __restrict__ Ab, const float* __restrict__ Bb,
    const float* __restrict__ Vb, const float* __restrict__ Ub,
    unsigned short* __restrict__ hAb, unsigned short* __restrict__ hBb,
    unsigned short* __restrict__ hVb, float* __restrict__ hU, int N)
{
    __shared__ unsigned short lbf[32768];  // 64 KB
    const int tid = threadIdx.x, lane = tid & 63, wave = tid >> 6;
    const int cg = blockIdx.y;
    {
        const f32x4* src = (const f32x4*)(BfragN + (size_t)cg * 32768);
        f32x4* dst = (f32x4*)lbf;
        for (int i = tid; i < 4096; i += 256) dst[i] = src[i];
    }
    const int rowWave = blockIdx.x * 256 + wave * 64;
    short8 afr[4][4];
    #pragma unroll
    for (int rt = 0; rt < 4; ++rt) {
        int row = rowWave + rt * 16 + (lane & 15);
        row = min(row, N - 1);
        const float* hp = h + (size_t)row * D + (lane >> 4) * 8;
        #pragma unroll
        for (int kc = 0; kc < 4; ++kc) {
            f32x4 x0 = *(const f32x4*)(hp + kc * 32);
            f32x4 x1 = *(const f32x4*)(hp + kc * 32 + 4);
            afr[rt][kc] = pack8(x0, x1);
        }
    }
    __syncthreads();
    #pragma unroll 1
    for (int ct = 0; ct < 16; ++ct) {
        f32x4 acc[4];
        #pragma unroll
        for (int rt = 0; rt < 4; ++rt) acc[rt] = (f32x4){0.f, 0.f, 0.f, 0.f};
        #pragma unroll
        for (int kc = 0; kc < 4; ++kc) {
            short8 bfr = *(const short8*)(lbf + ((size_t)(ct * 4 + kc) * 64 + lane) * 8);
            #pragma unroll
            for (int rt = 0; rt < 4; ++rt)
                acc[rt] = __builtin_amdgcn_mfma_f32_16x16x32_bf16(afr[rt][kc], bfr, acc[rt], 0, 0, 0);
        }
        int n512 = cg * 256 + ct * 16 + (lane & 15);
        int m = n512 >> 7, d = n512 & 127;
        const float* bias = (m == 0) ? Ab : (m == 1) ? Bb : (m == 2) ? Vb : Ub;
        float bv = bias[d];
        unsigned short* tbl = (m == 0) ? hAb : (m == 1) ? hBb : hVb;
        #pragma unroll
        for (int rt = 0; rt < 4; ++rt) {
            int rbase = rowWave + rt * 16 + ((lane >> 4) * 4);
            #pragma unroll
            for (int j = 0; j < 4; ++j) {
                int row = rbase + j;
                if (row < N) {
                    float val = acc[rt][j] + bv;
                    if (m < 3) tbl[(size_t)row * D + d] = f2bf(val);
                    else       hU[(size_t)row * D + d] = val;
                }
            }
        }
    }
}

// ---------------------------------------------------------------------------
// K2: edge GEMM eta = e@Cw + Cb + hA[s] + hB[r]; eta f32 -> e_new region of
// d_out (overwritten in-place by edge_bn). BN stats: shfl reduce + direct
// spread atomics (no stats LDS -> 32KB LDS -> 5 blocks/CU).
// ---------------------------------------------------------------------------
__global__ void __launch_bounds__(256) edge_gemm(
    const float* __restrict__ e, const int* __restrict__ senders,
    const int* __restrict__ receivers, const unsigned short* __restrict__ BfragC,
    const float* __restrict__ Cb, const unsigned short* __restrict__ hAb,
    const unsigned short* __restrict__ hBb, float* __restrict__ etaout,
    float* __restrict__ estats, int E)
{
    __shared__ unsigned short lbf[16384];   // exactly 32 KB
    const int tid = threadIdx.x, lane = tid & 63;
    {
        const f32x4* src = (const f32x4*)BfragC;
        f32x4* dst = (f32x4*)lbf;
        for (int i = tid; i < 2048; i += 256) dst[i] = src[i];
    }
    const int ebase = blockIdx.x * 256 + (tid >> 6) * 64;
    short8 afr[4][4];
    #pragma unroll
    for (int rt = 0; rt < 4; ++rt) {
        int row = ebase + rt * 16 + (lane & 15);
        row = min(row, E - 1);
        const float* ep = e + (size_t)row * D + (lane >> 4) * 8;
        #pragma unroll
        for (int kc = 0; kc < 4; ++kc) {
            f32x4 x0 = *(const f32x4*)(ep + kc * 32);
            f32x4 x1 = *(const f32x4*)(ep + kc * 32 + 4);
            afr[rt][kc] = pack8(x0, x1);
        }
    }
    int sidx[4][4], ridx[4][4];
    #pragma unroll
    for (int rt = 0; rt < 4; ++rt) {
        #pragma unroll
        for (int j = 0; j < 4; ++j) {
            int ed = ebase + rt * 16 + ((lane >> 4) * 4) + j;
            int ec = min(ed, E - 1);
            sidx[rt][j] = senders[ec];
            ridx[rt][j] = receivers[ec];
        }
    }
    __syncthreads();
    float* sb = estats + (blockIdx.x & 31) * 256;
    #pragma unroll 1
    for (int ct = 0; ct < 8; ++ct) {
        f32x4 acc[4];
        #pragma unroll
        for (int rt = 0; rt < 4; ++rt) acc[rt] = (f32x4){0.f, 0.f, 0.f, 0.f};
        #pragma unroll
        for (int kc = 0; kc < 4; ++kc) {
            short8 bfr = *(const short8*)(lbf + ((size_t)(ct * 4 + kc) * 64 + lane) * 8);
            #pragma unroll
            for (int rt = 0; rt < 4; ++rt)
                acc[rt] = __builtin_amdgcn_mfma_f32_16x16x32_bf16(afr[rt][kc], bfr, acc[rt], 0, 0, 0);
        }
        int col = ct * 16 + (lane & 15);
        float cb = Cb[col];
        float ps = 0.f, ps2 = 0.f;
        #pragma unroll
        for (int rt = 0; rt < 4; ++rt) {
            int rbase = ebase + rt * 16 + ((lane >> 4) * 4);
            #pragma unroll
            for (int j = 0; j < 4; ++j) {
                int ed = rbase + j;
                if (ed < E) {
                    float v = acc[rt][j] + cb
                            + bf2f(hAb[(size_t)sidx[rt][j] * D + col])
                            + bf2f(hBb[(size_t)ridx[rt][j] * D + col]);
                    etaout[(size_t)ed * D + col] = v;
                    ps  += v;
                    ps2 += v * v;
                }
            }
        }
        ps  += __shfl_xor(ps, 16);  ps  += __shfl_xor(ps, 32);
        ps2 += __shfl_xor(ps2, 16); ps2 += __shfl_xor(ps2, 32);
        if (lane < 16) {
            unsafeAtomicAdd(sb + col, ps);
            unsafeAtomicAdd(sb + 128 + col, ps2);
        }
    }
}

// ---------------------------------------------------------------------------
// finalize BN stats: 32 spread copies -> scale/shift vectors
// ---------------------------------------------------------------------------
__global__ void finalize_stats(const float* __restrict__ stats,
    const float* __restrict__ scale, const float* __restrict__ offset,
    float* __restrict__ scsh, float cnt)
{
    int c = threadIdx.x;
    if (c >= 128) return;
    float s = 0.f, s2 = 0.f;
    for (int b = 0; b < 32; ++b) { s += stats[b * 256 + c]; s2 += stats[b * 256 + 128 + c]; }
    float mean = s / cnt;
    float var  = fmaxf(s2 / cnt - mean * mean, 0.f);
    float rs   = rsqrtf(var + 1e-5f);
    float sc   = scale[c] * rs;
    scsh[c]       = sc;
    scsh[128 + c] = offset[c] - mean * sc;
}

// ---------------------------------------------------------------------------
// K3: edge BN apply (pure streaming, NO atomics): e_new = e + relu(BN(eta))
// ---------------------------------------------------------------------------
__global__ void __launch_bounds__(256) edge_bn_kernel(
    const float* __restrict__ e, const float* __restrict__ scsh,
    float* __restrict__ e_out, int total4)
{
    int idx = blockIdx.x * 256 + threadIdx.x;
    if (idx >= total4) return;
    size_t off = (size_t)idx * 4;
    int c0 = (int)(off & 127);
    f32x4 ev = *(const f32x4*)(e + off);
    f32x4 et = *(const f32x4*)(e_out + off);   // eta from edge_gemm
    f32x4 sc = *(const f32x4*)(scsh + c0);
    f32x4 sh = *(const f32x4*)(scsh + 128 + c0);
    f32x4 en;
    #pragma unroll
    for (int k = 0; k < 4; ++k) {
        float f = fmaxf(et[k] * sc[k] + sh[k], 0.f);
        en[k] = ev[k] + f;
    }
    *(f32x4*)(e_out + off) = en;
}

// ---------------------------------------------------------------------------
// CSR build: histogram -> single-block scan -> fill
// ---------------------------------------------------------------------------
__global__ void __launch_bounds__(256) csr_hist(
    const int* __restrict__ senders, int* __restrict__ counts, int E)
{
    int i = blockIdx.x * 256 + threadIdx.x;
    if (i < E) atomicAdd(&counts[senders[i]], 1);
}

__global__ void __launch_bounds__(1024) csr_scan(
    const int* __restrict__ counts, int* __restrict__ rowstart,
    int* __restrict__ cursor, int N)
{
    __shared__ int psum[1024];
    int tid = threadIdx.x;
    int chunk = (N + 1023) / 1024;
    int lo = tid * chunk, hi = min(lo + chunk, N);
    if (lo > N) lo = N;
    if (hi < lo) hi = lo;
    int s = 0;
    for (int i = lo; i < hi; ++i) s += counts[i];
    psum[tid] = s;
    __syncthreads();
    for (int off = 1; off < 1024; off <<= 1) {
        int v = (tid >= off) ? psum[tid - off] : 0;
        __syncthreads();
        psum[tid] += v;
        __syncthreads();
    }
    int base = (tid == 0) ? 0 : psum[tid - 1];
    for (int i = lo; i < hi; ++i) {
        rowstart[i] = base;
        cursor[i]   = base;
        base += counts[i];
    }
    if (tid == 1023) rowstart[N] = psum[1023];
}

__global__ void __launch_bounds__(256) csr_fill(
    const int* __restrict__ senders, int* __restrict__ cursor,
    int* __restrict__ elist, int E)
{
    int i = blockIdx.x * 256 + threadIdx.x;
    if (i < E) {
        int pos = atomicAdd(&cursor[senders[i]], 1);
        elist[pos] = i;
    }
}

// ---------------------------------------------------------------------------
// K4: node aggregation PULL: walk edge list, accumulate w=sigmoid(e_new) and
// hV[recv]*w in registers (2-way unrolled for load ILP); fused
// node_feat = hU + a/(w+1e-6) + BN stats partials.
// Block = 256 threads = 2 nodes x 128 cols.
// ---------------------------------------------------------------------------
__global__ void __launch_bounds__(256) node_agg_kernel(
    const float* __restrict__ e_new, const int* __restrict__ receivers,
    const int* __restrict__ rowstart, const int* __restrict__ elist,
    const unsigned short* __restrict__ hVb, const float* __restrict__ hU,
    float* __restrict__ nf, float* __restrict__ nstats, int N)
{
    __shared__ float lsum[128], lsq[128];
    const int half = threadIdx.x >> 7;     // 0 or 1
    const int c    = threadIdx.x & 127;
    const int n    = blockIdx.x * 2 + half;
    float v = 0.f;
    if (n < N) {
        float w = 0.f, a = 0.f;
        int lo = rowstart[n], hi = rowstart[n + 1];
        int k = lo;
        for (; k + 1 < hi; k += 2) {
            int e0 = elist[k], e1 = elist[k + 1];
            int r0 = receivers[e0], r1 = receivers[e1];
            float ev0 = e_new[(size_t)e0 * D + c];
            float ev1 = e_new[(size_t)e1 * D + c];
            float hv0 = bf2f(hVb[(size_t)r0 * D + c]);
            float hv1 = bf2f(hVb[(size_t)r1 * D + c]);
            float s0 = 1.f / (1.f + __expf(-ev0));
            float s1 = 1.f / (1.f + __expf(-ev1));
            a += hv0 * s0 + hv1 * s1;
            w += s0 + s1;
        }
        if (k < hi) {
            int e0 = elist[k];
            int r0 = receivers[e0];
            float ev0 = e_new[(size_t)e0 * D + c];
            float s0 = 1.f / (1.f + __expf(-ev0));
            a += bf2f(hVb[(size_t)r0 * D + c]) * s0;
            w += s0;
        }
        v = hU[(size_t)n * D + c] + a / (w + 1e-6f);
        nf[(size_t)n * D + c] = v;
    }
    if (half == 0) { lsum[c] = v;  lsq[c] = v * v; }
    __syncthreads();
    if (half == 1) { lsum[c] += v; lsq[c] += v * v; }
    __syncthreads();
    if (half == 0) {
        float* sb = nstats + (blockIdx.x & 31) * 256;
        unsafeAtomicAdd(sb + c, lsum[c]);
        unsafeAtomicAdd(sb + 128 + c, lsq[c]);
    }
}

// ---------------------------------------------------------------------------
// K5: h_new = h + relu(BN(node_feat))
// ---------------------------------------------------------------------------
__global__ void __launch_bounds__(256) node_out_kernel(
    const float* __restrict__ h, const float* __restrict__ nf,
    const float* __restrict__ scsh, float* __restrict__ out, int N)
{
    int idx = blockIdx.x * 256 + threadIdx.x;
    if (idx >= N * 32) return;
    size_t i4 = (size_t)idx * 4;
    int c0 = (int)(i4 & 127);
    f32x4 hh = *(const f32x4*)(h + i4);
    f32x4 v  = *(const f32x4*)(nf + i4);
    f32x4 sc = *(const f32x4*)(scsh + c0);
    f32x4 sh = *(const f32x4*)(scsh + 128 + c0);
    f32x4 o;
    #pragma unroll
    for (int k = 0; k < 4; ++k) {
        float f = fmaxf(v[k] * sc[k] + sh[k], 0.f);
        o[k] = hh[k] + f;
    }
    *(f32x4*)(out + i4) = o;
}

// ---------------------------------------------------------------------------
extern "C" void kernel_launch(void* const* d_in, const int* in_sizes, int n_in,
                              void* d_out, int out_size, void* d_ws, size_t ws_size,
                              hipStream_t stream)
{
    const float* h  = (const float*)d_in[0];
    const float* e  = (const float*)d_in[1];
    const int* senders   = (const int*)d_in[2];
    const int* receivers = (const int*)d_in[3];
    const float* Aw = (const float*)d_in[4];
    const float* Ab = (const float*)d_in[5];
    const float* Bw = (const float*)d_in[6];
    const float* Bb = (const float*)d_in[7];
    const float* Cw = (const float*)d_in[8];
    const float* Cb = (const float*)d_in[9];
    const float* Uw = (const float*)d_in[10];
    const float* Ub = (const float*)d_in[11];
    const float* Vw = (const float*)d_in[12];
    const float* Vb = (const float*)d_in[13];
    const float* bnEs = (const float*)d_in[14];
    const float* bnEo = (const float*)d_in[15];
    const float* bnNs = (const float*)d_in[16];
    const float* bnNo = (const float*)d_in[17];

    const int N = in_sizes[0] / D;   // 50000
    const int E = in_sizes[1] / D;   // 600000

    float* out   = (float*)d_out;
    float* out_h = out;
    float* out_e = out + (size_t)N * D;

    // workspace layout (f32 units); ~93 MB in d_ws
    float* ws     = (float*)d_ws;
    float* hU     = ws;                     // N*D f32
    float* nf     = hU + (size_t)N * D;     // N*D f32
    float* estats = nf + (size_t)N * D;     // 32*256
    float* nstats = estats + 32 * 256;      // 32*256
    float* scsh_e = nstats + 32 * 256;      // 256
    float* scsh_n = scsh_e + 256;           // 256
    int* counts   = (int*)(scsh_n + 256);   // N
    int* rowstart = counts + N;             // N+1
    int* cursor   = rowstart + N + 1;       // N
    int* elist    = cursor + N;             // E
    unsigned short* hAb = (unsigned short*)(elist + E);  // N*D bf16
    unsigned short* hBb = hAb + (size_t)N * D;
    unsigned short* hVb = hBb + (size_t)N * D;
    unsigned short* BfragC = hVb + (size_t)N * D;        // 16384 ushort
    unsigned short* BfragN = BfragC + 16384;             // 65536 ushort

    // zero estats + nstats + scsh (overwritten anyway) + counts (contiguous)
    hipMemsetAsync(estats, 0, (size_t)(2 * 32 * 256 + 2 * 256 + N) * sizeof(float), stream);

    prep_frags<<<40, 256, 0, stream>>>(Aw, Bw, Cw, Uw, Vw, BfragC, BfragN);

    // CSR build (independent of GEMMs)
    csr_hist<<<(E + 255) / 256, 256, 0, stream>>>(senders, counts, E);
    csr_scan<<<1, 1024, 0, stream>>>(counts, rowstart, cursor, N);
    csr_fill<<<(E + 255) / 256, 256, 0, stream>>>(senders, cursor, elist, E);

    dim3 g1((N + 255) / 256, 2);
    node_gemm<<<g1, 256, 0, stream>>>(h, BfragN, Ab, Bb, Vb, Ub, hAb, hBb, hVb, hU, N);

    edge_gemm<<<(E + 255) / 256, 256, 0, stream>>>(e, senders, receivers, BfragC, Cb,
                                                   hAb, hBb, out_e, estats, E);
    finalize_stats<<<1, 128, 0, stream>>>(estats, bnEs, bnEo, scsh_e, (float)E);

    edge_bn_kernel<<<(E * 32 + 255) / 256, 256, 0, stream>>>(e, scsh_e, out_e, E * 32);

    node_agg_kernel<<<(N + 1) / 2, 256, 0, stream>>>(out_e, receivers, rowstart, elist,
                                                     hVb, hU, nf, nstats, N);
    finalize_stats<<<1, 128, 0, stream>>>(nstats, bnNs, bnNo, scsh_n, (float)N);
    node_out_kernel<<<(N * 32 + 255) / 256, 256, 0, stream>>>(h, nf, scsh_n, out_h, N);
}